// Round 13
// baseline (101.498 us; speedup 1.0000x reference)
//
#include <hip/hip_runtime.h>

// AugmentedTripletLoss on MI355X.
// inputs [8192,128] f32, targets [8192] int, center [16,128] f32 -> scalar loss.
//
// v14b = v14 with the compile fix: int4 can't be "+v"-pinned as a whole
// ("tied indirect register inputs"); pin its 4 scalar components instead.
// v14 theory (unchanged): v12's skeleton (counted-vmcnt triple-buffer,
// 4-row-tile waves, verified conflict-free read pattern) with the one-hot
// class trick REVERTED: K 192 -> 128. The one-hot fold grew the BINDING
// pipe (MFMA floor 12.4 vs 8.3 us) and staging/LDS traffic by +50% to
// relieve VALU, which was never binding (epilogue-with-compare = 5.2 us
// < 8.3 us MFMA floor). Class mask now in the epilogue: per-strip targets
// staged to LDS (off the vmcnt counter, like sq); per-row targets in
// pinned registers. Schedule unchanged from v12: 8 stages x (64 cols x
// 256 B = 16 KB), triple-buffered (52 KB LDS), stage s top issues s+2's
// 4 gload_lds, stage end s_waitcnt vmcnt(4) + raw s_barrier (drain-0 only
// at tail). Read pattern mod-128-identical to v4/v8/v12/v13 (0 conflicts).

#define N_ROWS 8192
#define DIM 128
#define ROWB 256          // 128 bf16 dims * 2 B
#define NPROTO 16
#define NSTRIP 16         // 512-col strips
#define MARGIN_F 1.0f
#define EPS_F 1e-12f

typedef __attribute__((ext_vector_type(8))) short short8;   // 8 bf16 = 4 VGPRs
typedef __attribute__((ext_vector_type(4))) float float4v;  // MFMA acc

static __device__ __forceinline__ unsigned f2bf(float f) {
  // round-to-nearest-even bf16 (no NaN expected in this data)
  unsigned u = __float_as_uint(f);
  u += 0x7fffu + ((u >> 16) & 1u);
  return u >> 16;
}

static __device__ __forceinline__ void gload_lds16(const void* g, void* l) {
  __builtin_amdgcn_global_load_lds(
      (const __attribute__((address_space(1))) unsigned*)g,
      (__attribute__((address_space(3))) unsigned*)l, 16, 0, 0);
}

// 512 blocks x 16 rows. Fuses center normalization (redundant per block, 8 KB)
// + row prep: bf16 pack, ||x||^2, min dist-to-center.
__global__ void prep_kernel(const float* __restrict__ x,
                            const float* __restrict__ center,
                            char* __restrict__ xbf,
                            float* __restrict__ sq,
                            float* __restrict__ mindc,
                            float* __restrict__ out) {
  __shared__ float scn[NPROTO * DIM];  // normalized prototypes, 8 KB
  int tid = threadIdx.x;
  if (blockIdx.x == 0 && tid == 0) out[0] = 0.0f;  // zero loss accumulator
  int rloc = tid >> 4, l = tid & 15;
  {
    float v[8];
    float ss = 0.f;
#pragma unroll
    for (int j = 0; j < 8; ++j) {
      v[j] = center[rloc * DIM + l * 8 + j];
      ss += v[j] * v[j];
    }
    // 16-lane groups are contiguous in the wave -> masks 1..8 stay in-group
#pragma unroll
    for (int m = 1; m < 16; m <<= 1) ss += __shfl_xor(ss, m, 64);
    float inv = 1.0f / sqrtf(ss);
#pragma unroll
    for (int j = 0; j < 8; ++j) scn[rloc * DIM + l * 8 + j] = v[j] * inv;
  }
  __syncthreads();

  int row = blockIdx.x * 16 + rloc;
  float4 v0 = ((const float4*)x)[row * 32 + l * 2];
  float4 v1 = ((const float4*)x)[row * 32 + l * 2 + 1];
  float ss = v0.x * v0.x + v0.y * v0.y + v0.z * v0.z + v0.w * v0.w +
             v1.x * v1.x + v1.y * v1.y + v1.z * v1.z + v1.w * v1.w;
  float dots[NPROTO];
#pragma unroll
  for (int p = 0; p < NPROTO; ++p) {
    const float* c = &scn[p * DIM + l * 8];
    dots[p] = v0.x * c[0] + v0.y * c[1] + v0.z * c[2] + v0.w * c[3] +
              v1.x * c[4] + v1.y * c[5] + v1.z * c[6] + v1.w * c[7];
  }
#pragma unroll
  for (int m = 1; m < 16; m <<= 1) {
    ss += __shfl_xor(ss, m, 64);
#pragma unroll
    for (int p = 0; p < NPROTO; ++p) dots[p] += __shfl_xor(dots[p], m, 64);
  }
  // row-major bf16, 256 B/row, 16 B/lane coalesced
  uint4 pk;
  pk.x = f2bf(v0.x) | (f2bf(v0.y) << 16);
  pk.y = f2bf(v0.z) | (f2bf(v0.w) << 16);
  pk.z = f2bf(v1.x) | (f2bf(v1.y) << 16);
  pk.w = f2bf(v1.z) | (f2bf(v1.w) << 16);
  *(uint4*)(xbf + (size_t)row * ROWB + l * 16) = pk;
  if (l == 0) {
    float mind2 = INFINITY;
#pragma unroll
    for (int p = 0; p < NPROTO; ++p)
      mind2 = fminf(mind2, ss + 1.0f - 2.0f * dots[p]);  // cn is unit-norm
    sq[row] = ss;
    mindc[row] = fmaxf(sqrtf(fmaxf(mind2, 0.0f)), EPS_F);
  }
}

// Grid: 32 row-groups (256 rows) x 16 strips (512 cols) = 512 blocks.
// Block = 4 waves; wave w owns rows rg*256+w*64..+63 (4 row-tiles); shared
// triple-buffered 64-col stages; 8 stages x 4 phases of 16 cols.
// Counted vmcnt(4) + raw s_barrier per stage (never drain-0 mid-loop).
// v = sq_c - 2*dot tracked (sqrt deferred); class mask in the epilogue.
__global__ __launch_bounds__(256, 1) void
pairdist_kernel(const char* __restrict__ xbf, const float* __restrict__ sq,
                const int* __restrict__ tgt,
                float* __restrict__ pmax, float* __restrict__ pmin) {
  __shared__ __align__(16) char bl[3][16384];   // 3 x (64 cols x 256 B)
  __shared__ __align__(16) float sqlds[512];    // strip ||x||^2, 2 KB
  __shared__ __align__(16) int tgtlds[512];     // strip targets, 2 KB
  const int wave = threadIdx.x >> 6, lane = threadIdx.x & 63;
  const int q = lane >> 4, l16 = lane & 15;
  const int rg = blockIdx.x >> 4, strip = blockIdx.x & 15;
  const int rowbase = rg * 256 + wave * 64;
  const int stripbase = strip * 512;

  // T21 staging offsets: LDS dest linear (base + tid*16); XOR swizzle
  // o' = o ^ ((col&7)<<4) pre-applied to the per-lane GLOBAL source and to
  // the ds_read address below (same involution both sides).
  const int slot = threadIdx.x;
  const char* const srcstrip = xbf + (size_t)stripbase * ROWB;
  int soff[4];
#pragma unroll
  for (int r = 0; r < 4; ++r) {
    int o = r * 4096 + slot * 16;
    int c = o >> 8;  // column (256 B/row)
    soff[r] = c * ROWB + ((o & 255) ^ ((c & 7) << 4));
  }

  auto stage = [&](int s, char* buf) {
    const char* g = srcstrip + (size_t)s * 16384;  // 64 cols * 256 B
#pragma unroll
    for (int r = 0; r < 4; ++r)
      gload_lds16(g + soff[r], buf + r * 4096 + wave * 1024);
  };

  // A-frags + row-targets FIRST: their compiler waits land at the pins,
  // BEFORE the staging issue -> they never retire staging loads.
  // A[m=l16][k=q*8+j], 4 row-tiles x 4 k-chunks.
  short8 a[4][4];
#pragma unroll
  for (int rt = 0; rt < 4; ++rt) {
    const char* ar = xbf + (size_t)(rowbase + rt * 16 + l16) * ROWB + q * 16;
#pragma unroll
    for (int kc = 0; kc < 4; ++kc) a[rt][kc] = *(const short8*)(ar + kc * 64);
  }
  // row targets: acc elem (rt,r) is row rowbase+rt*16+q*4+r -> 4 ints per rt
  int trow[4][4];
#pragma unroll
  for (int rt = 0; rt < 4; ++rt) {
    int4 t4 = ((const int4*)tgt)[(rowbase >> 2) + rt * 4 + q];
    trow[rt][0] = t4.x; trow[rt][1] = t4.y;
    trow[rt][2] = t4.z; trow[rt][3] = t4.w;
  }
#pragma unroll
  for (int rt = 0; rt < 4; ++rt) {
#pragma unroll
    for (int kc = 0; kc < 4; ++kc)
      asm volatile("" : "+v"(a[rt][kc]));  // anti-remat/force-wait pin
#pragma unroll
    for (int r = 0; r < 4; ++r)
      asm volatile("" : "+v"(trow[rt][r]));  // scalar pins (int4 can't tie)
  }

  // Staging issue: sq (waves 0-1), tgt (waves 2-3), stage 0 (4), stage 1 (4).
  if (wave < 2)
    gload_lds16((const char*)(sq + stripbase) + wave * 1024 + lane * 16,
                (char*)sqlds + wave * 1024 + lane * 16);
  else
    gload_lds16((const char*)(tgt + stripbase) + (wave - 2) * 1024 + lane * 16,
                (char*)tgtlds + (wave - 2) * 1024 + lane * 16);
  stage(0, bl[0]);
  stage(1, bl[1]);

  // Swizzled LDS read offsets: phase p adds p*4096 additively
  // ((p*16+l16)&7 == l16&7). Pattern is mod-128-identical to v4/v8/v12/v13
  // (measured 0 bank conflicts).
  int roffb[4];
#pragma unroll
  for (int kc = 0; kc < 4; ++kc)
    roffb[kc] = (l16 * ROWB + kc * 64 + q * 16) ^ ((l16 & 7) << 4);

  float maxp[16], minn[16];
#pragma unroll
  for (int i = 0; i < 16; ++i) { maxp[i] = -INFINITY; minn[i] = INFINITY; }

  // Retire sq/tgt + stage 0; keep stage 1's 4 loads in flight across the
  // barrier (per-wave accounting; the barrier universalizes).
  asm volatile("s_waitcnt vmcnt(4)" ::: "memory");
  __builtin_amdgcn_s_barrier();
  asm volatile("" ::: "memory");  // compiler fence: no ds_read hoisting

#pragma unroll 1
  for (int s = 0; s < 8; ++s) {
    // Issue stage s+2 into bl[(s+2)%3]. Safe: that buffer was last read at
    // stage s-1, and every wave passed the end-of-(s-1) barrier.
    if (s + 2 < 8) stage(s + 2, bl[(s + 2) % 3]);
    const char* cur = bl[s % 3];
#pragma unroll
    for (int p = 0; p < 4; ++p) {
      const char* bufp = cur + p * 4096;
      float sqc = sqlds[s * 64 + p * 16 + l16];  // LDS: off the vmcnt counter
      int tcc = tgtlds[s * 64 + p * 16 + l16];   // col target
      short8 b[4];
#pragma unroll
      for (int kc = 0; kc < 4; ++kc)
        b[kc] = *(const short8*)(bufp + roffb[kc]);
      float4v acc[4];
#pragma unroll
      for (int rt = 0; rt < 4; ++rt) acc[rt] = (float4v){0.f, 0.f, 0.f, 0.f};
      __builtin_amdgcn_s_setprio(1);  // T5: favor the MFMA cluster
#pragma unroll
      for (int kc = 0; kc < 4; ++kc)
#pragma unroll
        for (int rt = 0; rt < 4; ++rt)  // 4 independent acc chains
          acc[rt] = __builtin_amdgcn_mfma_f32_16x16x32_bf16(a[rt][kc], b[kc],
                                                            acc[rt], 0, 0, 0);
      __builtin_amdgcn_s_setprio(0);
      // C/D layout: col = lane&15, row = q*4 + reg (m89-verified).
      // Class mask in epilogue: select on (col target == row target).
#pragma unroll
      for (int rt = 0; rt < 4; ++rt)
#pragma unroll
        for (int r = 0; r < 4; ++r) {
          float v = fmaf(-2.0f, acc[rt][r], sqc);  // dist2 = sq_row + v
          bool sm = (tcc == trow[rt][r]);
          int idx = rt * 4 + r;
          maxp[idx] = sm ? fmaxf(maxp[idx], v) : maxp[idx];
          minn[idx] = sm ? minn[idx] : fminf(minn[idx], v);
        }
    }
    // Stage end: retire stage s+1's 4 loads (oldest), keep s+2's 4 in
    // flight. Drain-0 only at the tail.
    if (s < 7) {
      if (s + 2 < 8)
        asm volatile("s_waitcnt vmcnt(4)" ::: "memory");
      else
        asm volatile("s_waitcnt vmcnt(0)" ::: "memory");
      __builtin_amdgcn_s_barrier();
      asm volatile("" ::: "memory");
    }
  }

  // reduce across the 16 lanes of each quad (xor masks 1..8 stay in-group)
#pragma unroll
  for (int m = 1; m < 16; m <<= 1)
#pragma unroll
    for (int i = 0; i < 16; ++i) {
      maxp[i] = fmaxf(maxp[i], __shfl_xor(maxp[i], m, 64));
      minn[i] = fminf(minn[i], __shfl_xor(minn[i], m, 64));
    }
  // waves own disjoint rows -> no cross-wave reduce; direct scattered store
  if (l16 == 0) {
    float* pM = pmax + (size_t)strip * N_ROWS + rowbase + q * 4;
    float* pm = pmin + (size_t)strip * N_ROWS + rowbase + q * 4;
#pragma unroll
    for (int rt = 0; rt < 4; ++rt)
#pragma unroll
      for (int r = 0; r < 4; ++r) {
        pM[rt * 16 + r] = maxp[rt * 4 + r];
        pm[rt * 16 + r] = minn[rt * 4 + r];
      }
  }
}

__global__ void finalize_kernel(const float* __restrict__ pmax,
                                const float* __restrict__ pmin,
                                const float* __restrict__ sq,
                                const float* __restrict__ mindc,
                                float* __restrict__ out) {
  __shared__ float wsum[4];
  int i = blockIdx.x * 256 + threadIdx.x;  // 32 blocks x 256 = 8192 rows
  float maxv = -INFINITY, minv = INFINITY;
#pragma unroll
  for (int s = 0; s < NSTRIP; ++s) {
    maxv = fmaxf(maxv, pmax[s * N_ROWS + i]);
    minv = fminf(minv, pmin[s * N_ROWS + i]);
  }
  float si = sq[i];
  float dap = sqrtf(fmaxf(si + maxv, EPS_F));  // diagonal guarantees maxv>-inf
  // if no negative exists anywhere, minv stays +inf -> dist_an = dap + margin
  float dan = (minv > 1e37f) ? (dap + MARGIN_F) : sqrtf(fmaxf(si + minv, EPS_F));
  dan = fminf(dan, mindc[i]);
  float c = fmaxf(dap - dan + MARGIN_F, 0.0f) * (1.0f / (float)N_ROWS);
#pragma unroll
  for (int m = 1; m < 64; m <<= 1) c += __shfl_xor(c, m, 64);
  int lane = threadIdx.x & 63, wv = threadIdx.x >> 6;
  if (lane == 0) wsum[wv] = c;
  __syncthreads();
  if (threadIdx.x == 0) atomicAdd(out, wsum[0] + wsum[1] + wsum[2] + wsum[3]);
}

extern "C" void kernel_launch(void* const* d_in, const int* in_sizes, int n_in,
                              void* d_out, int out_size, void* d_ws, size_t ws_size,
                              hipStream_t stream) {
  const float* inputs = (const float*)d_in[0];
  const int* targets = (const int*)d_in[1];  // per harness: integer -> const int*
  const float* center = (const float*)d_in[2];
  char* ws = (char*)d_ws;
  // ws layout (all 256B-aligned):
  char* xbf    = ws;                       // 8192*256 B bf16 = 2 MB
  float* sq    = (float*)(ws + 2097152);   // 8192 f32 = 32 KB
  float* mindc = (float*)(ws + 2129920);   // 8192 f32 = 32 KB
  float* pmax  = (float*)(ws + 2162688);   // 16*8192 f32 = 512 KB
  float* pmin  = (float*)(ws + 2686976);   // 16*8192 f32 = 512 KB
  float* out   = (float*)d_out;

  prep_kernel<<<512, 256, 0, stream>>>(inputs, center, xbf, sq, mindc, out);
  pairdist_kernel<<<512, 256, 0, stream>>>(xbf, sq, targets, pmax, pmin);
  finalize_kernel<<<32, 256, 0, stream>>>(pmax, pmin, sq, mindc, out);
}

// Round 14
// 95.983 us; speedup vs baseline: 1.0575x; 1.0575x over previous
//
#include <hip/hip_runtime.h>

// AugmentedTripletLoss on MI355X.
// inputs [8192,128] f32, targets [8192] int, center [16,128] f32 -> scalar loss.
//
// v15 = the three individually-validated levers, combined for the first time:
//   (1) v8's TLP: 4 blocks/CU (best total 91.9us; totals correlate with
//       blocks/CU across v8/v13 > v12/v14b)
//   (2) v12/v13's counted-vmcnt triple-buffer (only change that raised
//       MfmaUtil 13 -> 21%)
//   (3) v14's K=128 (MFMA floor 12.4 -> 8.3us, staging/LDS -33%) -- only
//       ever tested at 2 blocks/CU where latency masked it (v14b: -3us).
// Geometry: 2-row-tile waves (A=32 VGPR, ~90 live regs, fits the 128-cap
// of launch_bounds(256,4) with margin), 1024 blocks (64 rg x 16 strips =
// exactly 4/CU), 16 stages x (32 cols x 256 B = 8 KB), triple-buffered
// (24 KB + 2 KB sq + 2 KB tgt = 28 KB LDS). Per-wave vmcnt accounting:
// 2 staging loads/stage -> steady-state s_waitcnt vmcnt(2) + raw s_barrier
// (drain-0 only at tail). Class mask in the epilogue (pinned scalar row
// targets, v14b-verified); sq/tgt staged to LDS so the loop's vmcnt
// carries ONLY staging loads. Read pattern mod-128-identical to
// v4/v8/v12/v13/v14b (measured 0 bank conflicts).

#define N_ROWS 8192
#define DIM 128
#define ROWB 256          // 128 bf16 dims * 2 B
#define NPROTO 16
#define NSTRIP 16         // 512-col strips
#define NSTAGE 16         // 32-col stages per strip
#define MARGIN_F 1.0f
#define EPS_F 1e-12f

typedef __attribute__((ext_vector_type(8))) short short8;   // 8 bf16 = 4 VGPRs
typedef __attribute__((ext_vector_type(4))) float float4v;  // MFMA acc

static __device__ __forceinline__ unsigned f2bf(float f) {
  // round-to-nearest-even bf16 (no NaN expected in this data)
  unsigned u = __float_as_uint(f);
  u += 0x7fffu + ((u >> 16) & 1u);
  return u >> 16;
}

static __device__ __forceinline__ void gload_lds16(const void* g, void* l) {
  __builtin_amdgcn_global_load_lds(
      (const __attribute__((address_space(1))) unsigned*)g,
      (__attribute__((address_space(3))) unsigned*)l, 16, 0, 0);
}

// 512 blocks x 16 rows. Fuses center normalization (redundant per block, 8 KB)
// + row prep: bf16 pack, ||x||^2, min dist-to-center.
__global__ void prep_kernel(const float* __restrict__ x,
                            const float* __restrict__ center,
                            char* __restrict__ xbf,
                            float* __restrict__ sq,
                            float* __restrict__ mindc,
                            float* __restrict__ out) {
  __shared__ float scn[NPROTO * DIM];  // normalized prototypes, 8 KB
  int tid = threadIdx.x;
  if (blockIdx.x == 0 && tid == 0) out[0] = 0.0f;  // zero loss accumulator
  int rloc = tid >> 4, l = tid & 15;
  {
    float v[8];
    float ss = 0.f;
#pragma unroll
    for (int j = 0; j < 8; ++j) {
      v[j] = center[rloc * DIM + l * 8 + j];
      ss += v[j] * v[j];
    }
    // 16-lane groups are contiguous in the wave -> masks 1..8 stay in-group
#pragma unroll
    for (int m = 1; m < 16; m <<= 1) ss += __shfl_xor(ss, m, 64);
    float inv = 1.0f / sqrtf(ss);
#pragma unroll
    for (int j = 0; j < 8; ++j) scn[rloc * DIM + l * 8 + j] = v[j] * inv;
  }
  __syncthreads();

  int row = blockIdx.x * 16 + rloc;
  float4 v0 = ((const float4*)x)[row * 32 + l * 2];
  float4 v1 = ((const float4*)x)[row * 32 + l * 2 + 1];
  float ss = v0.x * v0.x + v0.y * v0.y + v0.z * v0.z + v0.w * v0.w +
             v1.x * v1.x + v1.y * v1.y + v1.z * v1.z + v1.w * v1.w;
  float dots[NPROTO];
#pragma unroll
  for (int p = 0; p < NPROTO; ++p) {
    const float* c = &scn[p * DIM + l * 8];
    dots[p] = v0.x * c[0] + v0.y * c[1] + v0.z * c[2] + v0.w * c[3] +
              v1.x * c[4] + v1.y * c[5] + v1.z * c[6] + v1.w * c[7];
  }
#pragma unroll
  for (int m = 1; m < 16; m <<= 1) {
    ss += __shfl_xor(ss, m, 64);
#pragma unroll
    for (int p = 0; p < NPROTO; ++p) dots[p] += __shfl_xor(dots[p], m, 64);
  }
  // row-major bf16, 256 B/row, 16 B/lane coalesced
  uint4 pk;
  pk.x = f2bf(v0.x) | (f2bf(v0.y) << 16);
  pk.y = f2bf(v0.z) | (f2bf(v0.w) << 16);
  pk.z = f2bf(v1.x) | (f2bf(v1.y) << 16);
  pk.w = f2bf(v1.z) | (f2bf(v1.w) << 16);
  *(uint4*)(xbf + (size_t)row * ROWB + l * 16) = pk;
  if (l == 0) {
    float mind2 = INFINITY;
#pragma unroll
    for (int p = 0; p < NPROTO; ++p)
      mind2 = fminf(mind2, ss + 1.0f - 2.0f * dots[p]);  // cn is unit-norm
    sq[row] = ss;
    mindc[row] = fmaxf(sqrtf(fmaxf(mind2, 0.0f)), EPS_F);
  }
}

// Grid: 64 row-groups (128 rows) x 16 strips (512 cols) = 1024 blocks
// (exactly 4/CU). Block = 4 waves; wave w owns rows rg*128+w*32..+31
// (2 row-tiles); shared triple-buffered 32-col stages; 16 stages x 2
// phases of 16 cols. Counted vmcnt(2) + raw s_barrier per stage.
// v = sq_c - 2*dot tracked (sqrt deferred); class mask in the epilogue.
__global__ __launch_bounds__(256, 4) void
pairdist_kernel(const char* __restrict__ xbf, const float* __restrict__ sq,
                const int* __restrict__ tgt,
                float* __restrict__ pmax, float* __restrict__ pmin) {
  __shared__ __align__(16) char bl[3][8192];    // 3 x (32 cols x 256 B)
  __shared__ __align__(16) float sqlds[512];    // strip ||x||^2, 2 KB
  __shared__ __align__(16) int tgtlds[512];     // strip targets, 2 KB
  const int wave = threadIdx.x >> 6, lane = threadIdx.x & 63;
  const int q = lane >> 4, l16 = lane & 15;
  const int rg = blockIdx.x >> 4, strip = blockIdx.x & 15;
  const int rowbase = rg * 128 + wave * 32;
  const int stripbase = strip * 512;

  // T21 staging offsets: LDS dest linear (base + tid*16); XOR swizzle
  // o' = o ^ ((col&7)<<4) pre-applied to the per-lane GLOBAL source and to
  // the ds_read address below (same involution both sides).
  const int slot = threadIdx.x;
  const char* const srcstrip = xbf + (size_t)stripbase * ROWB;
  int soff[2];
#pragma unroll
  for (int r = 0; r < 2; ++r) {
    int o = r * 4096 + slot * 16;
    int c = o >> 8;  // column (256 B/row)
    soff[r] = c * ROWB + ((o & 255) ^ ((c & 7) << 4));
  }

  auto stage = [&](int s, char* buf) {
    const char* g = srcstrip + (size_t)s * 8192;  // 32 cols * 256 B
#pragma unroll
    for (int r = 0; r < 2; ++r)
      gload_lds16(g + soff[r], buf + r * 4096 + wave * 1024);
  };

  // A-frags + row-targets FIRST: their compiler waits land at the pins,
  // BEFORE the staging issue -> they never retire staging loads.
  // A[m=l16][k=q*8+j], 2 row-tiles x 4 k-chunks.
  short8 a[2][4];
#pragma unroll
  for (int rt = 0; rt < 2; ++rt) {
    const char* ar = xbf + (size_t)(rowbase + rt * 16 + l16) * ROWB + q * 16;
#pragma unroll
    for (int kc = 0; kc < 4; ++kc) a[rt][kc] = *(const short8*)(ar + kc * 64);
  }
  // row targets: acc elem (rt,r) is row rowbase+rt*16+q*4+r -> 4 ints per rt
  int trow[2][4];
#pragma unroll
  for (int rt = 0; rt < 2; ++rt) {
    int4 t4 = ((const int4*)tgt)[(rowbase >> 2) + rt * 4 + q];
    trow[rt][0] = t4.x; trow[rt][1] = t4.y;
    trow[rt][2] = t4.z; trow[rt][3] = t4.w;
  }
#pragma unroll
  for (int rt = 0; rt < 2; ++rt) {
#pragma unroll
    for (int kc = 0; kc < 4; ++kc)
      asm volatile("" : "+v"(a[rt][kc]));  // anti-remat/force-wait pin
#pragma unroll
    for (int r = 0; r < 4; ++r)
      asm volatile("" : "+v"(trow[rt][r]));  // scalar pins (int4 can't tie)
  }

  // Staging issue: sq (waves 0-1), tgt (waves 2-3), stage 0 (2), stage 1 (2).
  if (wave < 2)
    gload_lds16((const char*)(sq + stripbase) + wave * 1024 + lane * 16,
                (char*)sqlds + wave * 1024 + lane * 16);
  else
    gload_lds16((const char*)(tgt + stripbase) + (wave - 2) * 1024 + lane * 16,
                (char*)tgtlds + (wave - 2) * 1024 + lane * 16);
  stage(0, bl[0]);
  stage(1, bl[1]);

  // Swizzled LDS read offsets: phase p adds p*4096 additively
  // ((p*16+l16)&7 == l16&7). Pattern is mod-128-identical to
  // v4/v8/v12/v13/v14b (measured 0 bank conflicts).
  int roffb[4];
#pragma unroll
  for (int kc = 0; kc < 4; ++kc)
    roffb[kc] = (l16 * ROWB + kc * 64 + q * 16) ^ ((l16 & 7) << 4);

  float maxp[8], minn[8];
#pragma unroll
  for (int i = 0; i < 8; ++i) { maxp[i] = -INFINITY; minn[i] = INFINITY; }

  // Retire sq/tgt + stage 0 (3 oldest per wave); keep stage 1's 2 loads in
  // flight across the barrier (per-wave accounting; barrier universalizes).
  asm volatile("s_waitcnt vmcnt(2)" ::: "memory");
  __builtin_amdgcn_s_barrier();
  asm volatile("" ::: "memory");  // compiler fence: no ds_read hoisting

#pragma unroll 1
  for (int s = 0; s < NSTAGE; ++s) {
    // Issue stage s+2 into bl[(s+2)%3]. Safe: that buffer was last read at
    // stage s-1, and every wave passed the end-of-(s-1) barrier.
    if (s + 2 < NSTAGE) stage(s + 2, bl[(s + 2) % 3]);
    const char* cur = bl[s % 3];
#pragma unroll
    for (int p = 0; p < 2; ++p) {
      const char* bufp = cur + p * 4096;
      float sqc = sqlds[s * 32 + p * 16 + l16];  // LDS: off the vmcnt counter
      int tcc = tgtlds[s * 32 + p * 16 + l16];   // col target
      short8 b[4];
#pragma unroll
      for (int kc = 0; kc < 4; ++kc)
        b[kc] = *(const short8*)(bufp + roffb[kc]);
      float4v acc[2];
#pragma unroll
      for (int rt = 0; rt < 2; ++rt) acc[rt] = (float4v){0.f, 0.f, 0.f, 0.f};
      __builtin_amdgcn_s_setprio(1);  // T5: favor the MFMA cluster
#pragma unroll
      for (int kc = 0; kc < 4; ++kc)
#pragma unroll
        for (int rt = 0; rt < 2; ++rt)  // 2 independent acc chains
          acc[rt] = __builtin_amdgcn_mfma_f32_16x16x32_bf16(a[rt][kc], b[kc],
                                                            acc[rt], 0, 0, 0);
      __builtin_amdgcn_s_setprio(0);
      // C/D layout: col = lane&15, row = q*4 + reg (m89-verified).
      // Class mask in epilogue: select on (col target == row target).
#pragma unroll
      for (int rt = 0; rt < 2; ++rt)
#pragma unroll
        for (int r = 0; r < 4; ++r) {
          float v = fmaf(-2.0f, acc[rt][r], sqc);  // dist2 = sq_row + v
          bool sm = (tcc == trow[rt][r]);
          int idx = rt * 4 + r;
          maxp[idx] = sm ? fmaxf(maxp[idx], v) : maxp[idx];
          minn[idx] = sm ? minn[idx] : fminf(minn[idx], v);
        }
    }
    // Stage end: retire stage s+1's 2 loads (oldest), keep s+2's 2 in
    // flight. Drain-0 only at the tail.
    if (s < NSTAGE - 1) {
      if (s + 2 < NSTAGE)
        asm volatile("s_waitcnt vmcnt(2)" ::: "memory");
      else
        asm volatile("s_waitcnt vmcnt(0)" ::: "memory");
      __builtin_amdgcn_s_barrier();
      asm volatile("" ::: "memory");
    }
  }

  // reduce across the 16 lanes of each quad (xor masks 1..8 stay in-group)
#pragma unroll
  for (int m = 1; m < 16; m <<= 1)
#pragma unroll
    for (int i = 0; i < 8; ++i) {
      maxp[i] = fmaxf(maxp[i], __shfl_xor(maxp[i], m, 64));
      minn[i] = fminf(minn[i], __shfl_xor(minn[i], m, 64));
    }
  // waves own disjoint rows -> no cross-wave reduce; direct scattered store
  if (l16 == 0) {
    float* pM = pmax + (size_t)strip * N_ROWS + rowbase + q * 4;
    float* pm = pmin + (size_t)strip * N_ROWS + rowbase + q * 4;
#pragma unroll
    for (int rt = 0; rt < 2; ++rt)
#pragma unroll
      for (int r = 0; r < 4; ++r) {
        pM[rt * 16 + r] = maxp[rt * 4 + r];
        pm[rt * 16 + r] = minn[rt * 4 + r];
      }
  }
}

__global__ void finalize_kernel(const float* __restrict__ pmax,
                                const float* __restrict__ pmin,
                                const float* __restrict__ sq,
                                const float* __restrict__ mindc,
                                float* __restrict__ out) {
  __shared__ float wsum[4];
  int i = blockIdx.x * 256 + threadIdx.x;  // 32 blocks x 256 = 8192 rows
  float maxv = -INFINITY, minv = INFINITY;
#pragma unroll
  for (int s = 0; s < NSTRIP; ++s) {
    maxv = fmaxf(maxv, pmax[s * N_ROWS + i]);
    minv = fminf(minv, pmin[s * N_ROWS + i]);
  }
  float si = sq[i];
  float dap = sqrtf(fmaxf(si + maxv, EPS_F));  // diagonal guarantees maxv>-inf
  // if no negative exists anywhere, minv stays +inf -> dist_an = dap + margin
  float dan = (minv > 1e37f) ? (dap + MARGIN_F) : sqrtf(fmaxf(si + minv, EPS_F));
  dan = fminf(dan, mindc[i]);
  float c = fmaxf(dap - dan + MARGIN_F, 0.0f) * (1.0f / (float)N_ROWS);
#pragma unroll
  for (int m = 1; m < 64; m <<= 1) c += __shfl_xor(c, m, 64);
  int lane = threadIdx.x & 63, wv = threadIdx.x >> 6;
  if (lane == 0) wsum[wv] = c;
  __syncthreads();
  if (threadIdx.x == 0) atomicAdd(out, wsum[0] + wsum[1] + wsum[2] + wsum[3]);
}

extern "C" void kernel_launch(void* const* d_in, const int* in_sizes, int n_in,
                              void* d_out, int out_size, void* d_ws, size_t ws_size,
                              hipStream_t stream) {
  const float* inputs = (const float*)d_in[0];
  const int* targets = (const int*)d_in[1];  // per harness: integer -> const int*
  const float* center = (const float*)d_in[2];
  char* ws = (char*)d_ws;
  // ws layout (all 256B-aligned):
  char* xbf    = ws;                       // 8192*256 B bf16 = 2 MB
  float* sq    = (float*)(ws + 2097152);   // 8192 f32 = 32 KB
  float* mindc = (float*)(ws + 2129920);   // 8192 f32 = 32 KB
  float* pmax  = (float*)(ws + 2162688);   // 16*8192 f32 = 512 KB
  float* pmin  = (float*)(ws + 2686976);   // 16*8192 f32 = 512 KB
  float* out   = (float*)d_out;

  prep_kernel<<<512, 256, 0, stream>>>(inputs, center, xbf, sq, mindc, out);
  pairdist_kernel<<<1024, 256, 0, stream>>>(xbf, sq, targets, pmax, pmin);
  finalize_kernel<<<32, 256, 0, stream>>>(pmax, pmin, sq, mindc, out);
}